// Round 5
// baseline (89.112 us; speedup 1.0000x reference)
//
#include <hip/hip_runtime.h>
#include <hip/hip_bf16.h>

// NT-Xent loss, fused + symmetric. N=4096, D=256, T=0.5.
// sim is symmetric: one 256x256 panel-pair tile serves rowsums of BOTH panels
// (row-reduce for panel r, col-reduce for panel c). 528 = 32*33/2 blocks.
// d_ws: [reps bf16 2N*D | pos f32 N | partial f32 2N*SLOTS | bsum f32 32]
// partial[row][slot]: slot p = contribution from panel p; single writer/slot.
// loss_i = log(sum_j exp(sim_ij/T) - e^2) - pos_i/T ; out = mean(loss)

#define D      256
#define KC     8            // K-chunks of 32 elems (D/32)
#define RT     4            // row-tiles per wave -> 64 rows/wave
#define PAN    32           // number of 256-row panels (8192/256)
#define NBLK   (PAN * (PAN + 1) / 2)   // 528 panel pairs
#define BN     64           // B-columns staged in LDS per chunk
#define SLOTS  32           // partial slots per row (= PAN)
#define CEXP   2.885390081777926f  // 1/(T*ln2): exp(x/T) = 2^(x*CEXP)
#define E2     7.38905609893065f   // exp(1/T) = e^2, diagonal term
#define FBLK   32

typedef __bf16 bf16x8 __attribute__((ext_vector_type(8)));
typedef float  f32x4  __attribute__((ext_vector_type(4)));
typedef __attribute__((address_space(1))) const unsigned int* gas_t;
typedef __attribute__((address_space(3))) unsigned int*       las_t;

static __device__ __forceinline__ void gload_lds16(const void* g, void* l) {
    __builtin_amdgcn_global_load_lds((gas_t)(uintptr_t)g, (las_t)(uintptr_t)l, 16, 0, 0);
}

static __device__ __forceinline__ unsigned short f2bf(float x) {
    union { float f; unsigned u; } v; v.f = x;
    unsigned r = v.u + 0x7fffu + ((v.u >> 16) & 1u);   // RNE
    return (unsigned short)(r >> 16);
}

// Stage 32KB (64 rows x 512B) global->LDS, linear dest, source pre-swizzled
// so that swizzled ds_reads (byte ^ (row&7)<<4) see correct data (rule 21).
#define STAGE(bufp, srcp)                                                 \
    do {                                                                  \
        const char* s_ = (const char*)(srcp);                             \
        char* d_ = (char*)(bufp);                                         \
        _Pragma("unroll")                                                 \
        for (int i_ = 0; i_ < 8; ++i_) {                                  \
            int o_   = i_ * 4096 + threadIdx.x * 16;                      \
            int row_ = o_ >> 9;                                           \
            int cb_  = o_ & 511;                                          \
            gload_lds16(s_ + row_ * 512 + (cb_ ^ ((row_ & 7) << 4)),      \
                        d_ + o_);                                         \
        }                                                                 \
    } while (0)

#define LOAD_AFRAG(srcbase)                                               \
    do {                                                                  \
        const char* ab_ = (const char*)(srcbase);                         \
        _Pragma("unroll")                                                 \
        for (int rt_ = 0; rt_ < RT; ++rt_)                                \
            _Pragma("unroll")                                             \
            for (int kc_ = 0; kc_ < KC; ++kc_)                            \
                afrag[rt_][kc_] = *(const bf16x8*)(ab_ +                  \
                    (rt_ * 16 + lrow) * 512 + ((kc_ * 64 + lkb) ^ swz));  \
    } while (0)

// ---- Kernel A: row L2-normalize both inputs -> bf16 reps; fp32 positives ----
__global__ __launch_bounds__(64) void knorm(const float* __restrict__ zi,
                                            const float* __restrict__ zj,
                                            unsigned short* __restrict__ reps,
                                            float* __restrict__ pos, int n) {
    const int i = blockIdx.x;
    const int lane = threadIdx.x;
    const float4 a = ((const float4*)(zi + (size_t)i * D))[lane];
    const float4 b = ((const float4*)(zj + (size_t)i * D))[lane];
    float si = a.x*a.x + a.y*a.y + a.z*a.z + a.w*a.w;
    float sj = b.x*b.x + b.y*b.y + b.z*b.z + b.w*b.w;
    float sd = a.x*b.x + a.y*b.y + a.z*b.z + a.w*b.w;
    #pragma unroll
    for (int off = 32; off; off >>= 1) {
        si += __shfl_xor(si, off);
        sj += __shfl_xor(sj, off);
        sd += __shfl_xor(sd, off);
    }
    const float inv_i = 1.0f / fmaxf(sqrtf(si), 1e-12f);
    const float inv_j = 1.0f / fmaxf(sqrtf(sj), 1e-12f);
    if (lane == 0) pos[i] = sd * inv_i * inv_j;
    ushort4 pa, pb;
    pa.x = f2bf(a.x * inv_i); pa.y = f2bf(a.y * inv_i);
    pa.z = f2bf(a.z * inv_i); pa.w = f2bf(a.w * inv_i);
    pb.x = f2bf(b.x * inv_j); pb.y = f2bf(b.y * inv_j);
    pb.z = f2bf(b.z * inv_j); pb.w = f2bf(b.w * inv_j);
    ((ushort4*)(reps + (size_t)i * D))[lane]       = pa;
    ((ushort4*)(reps + (size_t)(i + n) * D))[lane] = pb;
}

// ---- Kernel B: symmetric panel-pair exp-rowsum ----
// Block = unordered panel pair (rpan <= cpan). 4 waves x 64 rows.
// rowsum (panel rpan rows over cpan cols) -> partial[row][cpan]
// colsum (panel cpan rows, off-diag only)  -> partial[col][rpan]
__global__ __launch_bounds__(256, 2) void krowsum(const unsigned short* __restrict__ reps,
                                                  float* __restrict__ partial) {
    __shared__ unsigned short buf[2][BN * D];   // 2 x 32 KB
    __shared__ float cs_lds[4][16][16];         // [wave][chunk*4+tile][col]
    const int lane = threadIdx.x & 63;
    const int w    = threadIdx.x >> 6;
    const int lrow = lane & 15;
    const int lkb  = (lane >> 4) * 16;
    const int swz  = (lrow & 7) << 4;

    // unrank blockIdx -> (rpan, cpan) with rpan <= cpan
    int bid = blockIdx.x, rpan = 0, rem = PAN;
    while (bid >= rem) { bid -= rem; ++rpan; --rem; }
    const int cpan = rpan + bid;
    const bool diag = (rpan == cpan);

    // ---- A prologue: stage 4x 64-row chunks through buf, coalesced ----
    bf16x8 afrag[RT][KC];
    const char* Ab = (const char*)reps + (size_t)rpan * 256 * 512;
    STAGE(&buf[0][0], Ab);
    STAGE(&buf[1][0], Ab + 32768);
    __syncthreads();
    if (w < 2) LOAD_AFRAG(&buf[w][0]);
    __syncthreads();
    STAGE(&buf[0][0], Ab + 2 * 32768);
    STAGE(&buf[1][0], Ab + 3 * 32768);
    __syncthreads();
    if (w >= 2) LOAD_AFRAG(&buf[w - 2][0]);
    __syncthreads();

    float rs[RT][4];
    #pragma unroll
    for (int rt = 0; rt < RT; ++rt)
        #pragma unroll
        for (int e = 0; e < 4; ++e) rs[rt][e] = 0.f;

    // ---- B main loop: 4 chunks of 64 cols, double-buffered ----
    const char* Bb = (const char*)reps + (size_t)cpan * 256 * 512;
    STAGE(&buf[0][0], Bb);
    __syncthreads();
    int cur = 0;
    for (int c = 0; c < 4; ++c) {
        if (c < 3) STAGE(&buf[cur ^ 1][0], Bb + (size_t)(c + 1) * 32768);
        const char* bb = (const char*)&buf[cur][0];
        float cs0 = 0.f, cs1 = 0.f, cs2 = 0.f, cs3 = 0.f;
        #pragma unroll
        for (int tp = 0; tp < 2; ++tp) {
            f32x4 acc[RT][2];
            #pragma unroll
            for (int rt = 0; rt < RT; ++rt) {
                acc[rt][0] = (f32x4){0.f, 0.f, 0.f, 0.f};
                acc[rt][1] = (f32x4){0.f, 0.f, 0.f, 0.f};
            }
            #pragma unroll
            for (int kc = 0; kc < KC; ++kc) {
                const int kb = (kc * 64 + lkb) ^ swz;
                bf16x8 bf0 = *(const bf16x8*)(bb + ((tp * 2 + 0) * 16 + lrow) * 512 + kb);
                bf16x8 bf1 = *(const bf16x8*)(bb + ((tp * 2 + 1) * 16 + lrow) * 512 + kb);
                #pragma unroll
                for (int rt = 0; rt < RT; ++rt) {
                    acc[rt][0] = __builtin_amdgcn_mfma_f32_16x16x32_bf16(
                        afrag[rt][kc], bf0, acc[rt][0], 0, 0, 0);
                    acc[rt][1] = __builtin_amdgcn_mfma_f32_16x16x32_bf16(
                        afrag[rt][kc], bf1, acc[rt][1], 0, 0, 0);
                }
            }
            // C/D layout: col = lane&15, row = (lane>>4)*4 + e  [m89]
            #pragma unroll
            for (int rt = 0; rt < RT; ++rt)
                #pragma unroll
                for (int e = 0; e < 4; ++e) {
                    float e0 = __builtin_amdgcn_exp2f(acc[rt][0][e] * CEXP);
                    float e1 = __builtin_amdgcn_exp2f(acc[rt][1][e] * CEXP);
                    rs[rt][e] += e0 + e1;
                    if (tp == 0) { cs0 += e0; cs1 += e1; }
                    else         { cs2 += e0; cs3 += e1; }
                }
        }
        if (!diag) {
            // colsum: reduce over the 4 row-groups (lane>>4)
            cs0 += __shfl_xor(cs0, 16); cs0 += __shfl_xor(cs0, 32);
            cs1 += __shfl_xor(cs1, 16); cs1 += __shfl_xor(cs1, 32);
            cs2 += __shfl_xor(cs2, 16); cs2 += __shfl_xor(cs2, 32);
            cs3 += __shfl_xor(cs3, 16); cs3 += __shfl_xor(cs3, 32);
            if (lane < 16) {
                cs_lds[w][c * 4 + 0][lane] = cs0;
                cs_lds[w][c * 4 + 1][lane] = cs1;
                cs_lds[w][c * 4 + 2][lane] = cs2;
                cs_lds[w][c * 4 + 3][lane] = cs3;
            }
        }
        __syncthreads();   // drains staging vmcnt + ds reads; publishes cs_lds[c]
        cur ^= 1;
    }

    // ---- rowsum: reduce 16 col-lanes, write partial[row][cpan] ----
    #pragma unroll
    for (int rt = 0; rt < RT; ++rt)
        #pragma unroll
        for (int e = 0; e < 4; ++e)
            #pragma unroll
            for (int off = 1; off < 16; off <<= 1)
                rs[rt][e] += __shfl_xor(rs[rt][e], off);
    const int rbase = rpan * 256 + w * 64;
    if ((lane & 15) == 0) {
        #pragma unroll
        for (int rt = 0; rt < RT; ++rt) {
            const int rg = rbase + rt * 16 + (lane >> 4) * 4;
            #pragma unroll
            for (int e = 0; e < 4; ++e)
                partial[(size_t)(rg + e) * SLOTS + cpan] = rs[rt][e];
        }
    }

    // ---- colsum: cross-wave sum, write partial[col][rpan] ----
    if (!diag) {
        const int ct  = threadIdx.x >> 4;    // chunk*4 + tile (16 combos)
        const int col = threadIdx.x & 15;
        const float v = cs_lds[0][ct][col] + cs_lds[1][ct][col]
                      + cs_lds[2][ct][col] + cs_lds[3][ct][col];
        const int gcol = cpan * 256 + (ct >> 2) * 64 + (ct & 3) * 16 + col;
        partial[(size_t)gcol * SLOTS + rpan] = v;
    }
}

// ---- Kernel C1: per-row loss, block partial sums ----
__global__ __launch_bounds__(256) void kfinal1(const float* __restrict__ partial,
                                               const float* __restrict__ pos,
                                               float* __restrict__ bsum,
                                               int twoN, int n) {
    __shared__ float red[256];
    const int r = blockIdx.x * 256 + threadIdx.x;
    float s = 0.f;
    if (r < twoN) {
        const f32x4* pr = (const f32x4*)(partial + (size_t)r * SLOTS);
        f32x4 v = pr[0];
        #pragma unroll
        for (int q = 1; q < SLOTS / 4; ++q) {
            f32x4 u = pr[q];
            v[0] += u[0]; v[1] += u[1]; v[2] += u[2]; v[3] += u[3];
        }
        float dsum = (v[0] + v[1]) + (v[2] + v[3]) - E2;
        const float p = pos[r < n ? r : r - n];
        s = logf(dsum) - 2.0f * p;        // pos/T with T=0.5
    }
    red[threadIdx.x] = s;
    __syncthreads();
    #pragma unroll
    for (int off = 128; off; off >>= 1) {
        if (threadIdx.x < off) red[threadIdx.x] += red[threadIdx.x + off];
        __syncthreads();
    }
    if (threadIdx.x == 0) bsum[blockIdx.x] = red[0];
}

// ---- Kernel C2: final mean ----
__global__ __launch_bounds__(64) void kfinal2(const float* __restrict__ bsum,
                                              float* __restrict__ out, int twoN) {
    float s = threadIdx.x < FBLK ? bsum[threadIdx.x] : 0.f;
    #pragma unroll
    for (int off = 32; off; off >>= 1) s += __shfl_xor(s, off);
    if (threadIdx.x == 0) out[0] = s / (float)twoN;
}

extern "C" void kernel_launch(void* const* d_in, const int* in_sizes, int n_in,
                              void* d_out, int out_size, void* d_ws, size_t ws_size,
                              hipStream_t stream) {
    const float* zi = (const float*)d_in[0];
    const float* zj = (const float*)d_in[1];
    const int n    = in_sizes[0] / D;   // 4096
    const int twoN = 2 * n;             // 8192

    unsigned short* reps = (unsigned short*)d_ws;                   // 2N*D bf16 = 4 MB
    float* pos     = (float*)((char*)d_ws + (size_t)twoN * D * 2);  // N f32
    float* partial = pos + n;                                       // 2N*SLOTS f32
    float* bsum    = partial + (size_t)twoN * SLOTS;                // FBLK f32
    float* out     = (float*)d_out;

    knorm<<<n, 64, 0, stream>>>(zi, zj, reps, pos, n);
    krowsum<<<NBLK, 256, 0, stream>>>(reps, partial);
    kfinal1<<<FBLK, 256, 0, stream>>>(partial, pos, bsum, twoN, n);
    kfinal2<<<1, 64, 0, stream>>>(bsum, out, twoN);
}

// Round 6
// 79.708 us; speedup vs baseline: 1.1180x; 1.1180x over previous
//
#include <hip/hip_runtime.h>
#include <hip/hip_bf16.h>

// NT-Xent loss, fused + symmetric. N=4096, D=256, T=0.5.
// One 256x256 panel-pair tile serves rowsums of BOTH panels (row-reduce for
// panel r, col-reduce for panel c). 528 = 32*33/2 blocks, 8 waves x 32 rows.
// d_ws: [reps bf16 2N*D | pos f32 N | partial f32 2N*SLOTS | bsum f32 32]
// partial[row][slot]: slot p = contribution from panel p; single writer/slot.
// loss_i = log(sum_j exp(sim_ij/T) - e^2) - pos_i/T ; out = mean(loss)

#define D      256
#define KC     8            // K-chunks of 32 elems (D/32)
#define RT     2            // row-tiles per wave -> 32 rows/wave (VGPR budget!)
#define PAN    32           // number of 256-row panels (8192/256)
#define NBLK   (PAN * (PAN + 1) / 2)   // 528 panel pairs
#define SLOTS  32           // partial slots per row (= PAN)
#define CEXP   2.885390081777926f  // 1/(T*ln2): exp(x/T) = 2^(x*CEXP)
#define E2     7.38905609893065f   // exp(1/T) = e^2, diagonal term
#define FBLK   32

typedef __bf16 bf16x8 __attribute__((ext_vector_type(8)));
typedef float  f32x4  __attribute__((ext_vector_type(4)));
typedef __attribute__((address_space(1))) const unsigned int* gas_t;
typedef __attribute__((address_space(3))) unsigned int*       las_t;

static __device__ __forceinline__ void gload_lds16(const void* g, void* l) {
    __builtin_amdgcn_global_load_lds((gas_t)(uintptr_t)g, (las_t)(uintptr_t)l, 16, 0, 0);
}

static __device__ __forceinline__ unsigned short f2bf(float x) {
    union { float f; unsigned u; } v; v.f = x;
    unsigned r = v.u + 0x7fffu + ((v.u >> 16) & 1u);   // RNE
    return (unsigned short)(r >> 16);
}

// Stage 32KB (64 rows x 512B) global->LDS with 512 threads (4 passes of 8KB).
// Linear LDS dest; source pre-swizzled so swizzled ds_reads see correct data.
#define STAGE(bufp, srcp)                                                 \
    do {                                                                  \
        const char* s_ = (const char*)(srcp);                             \
        char* d_ = (char*)(bufp);                                         \
        _Pragma("unroll")                                                 \
        for (int i_ = 0; i_ < 4; ++i_) {                                  \
            int o_   = i_ * 8192 + threadIdx.x * 16;                      \
            int row_ = o_ >> 9;                                           \
            int cb_  = o_ & 511;                                          \
            gload_lds16(s_ + row_ * 512 + (cb_ ^ ((row_ & 7) << 4)),      \
                        d_ + o_);                                         \
        }                                                                 \
    } while (0)

// ---- Kernel A: row L2-normalize both inputs -> bf16 reps; fp32 positives ----
__global__ __launch_bounds__(64) void knorm(const float* __restrict__ zi,
                                            const float* __restrict__ zj,
                                            unsigned short* __restrict__ reps,
                                            float* __restrict__ pos, int n) {
    const int i = blockIdx.x;
    const int lane = threadIdx.x;
    const float4 a = ((const float4*)(zi + (size_t)i * D))[lane];
    const float4 b = ((const float4*)(zj + (size_t)i * D))[lane];
    float si = a.x*a.x + a.y*a.y + a.z*a.z + a.w*a.w;
    float sj = b.x*b.x + b.y*b.y + b.z*b.z + b.w*b.w;
    float sd = a.x*b.x + a.y*b.y + a.z*b.z + a.w*b.w;
    #pragma unroll
    for (int off = 32; off; off >>= 1) {
        si += __shfl_xor(si, off);
        sj += __shfl_xor(sj, off);
        sd += __shfl_xor(sd, off);
    }
    const float inv_i = 1.0f / fmaxf(sqrtf(si), 1e-12f);
    const float inv_j = 1.0f / fmaxf(sqrtf(sj), 1e-12f);
    if (lane == 0) pos[i] = sd * inv_i * inv_j;
    ushort4 pa, pb;
    pa.x = f2bf(a.x * inv_i); pa.y = f2bf(a.y * inv_i);
    pa.z = f2bf(a.z * inv_i); pa.w = f2bf(a.w * inv_i);
    pb.x = f2bf(b.x * inv_j); pb.y = f2bf(b.y * inv_j);
    pb.z = f2bf(b.z * inv_j); pb.w = f2bf(b.w * inv_j);
    ((ushort4*)(reps + (size_t)i * D))[lane]       = pa;
    ((ushort4*)(reps + (size_t)(i + n) * D))[lane] = pb;
}

// ---- Kernel B: symmetric panel-pair exp-rowsum ----
// Block = unordered panel pair (rpan <= cpan). 8 waves x 32 rows.
// rowsum (panel rpan rows over cpan cols) -> partial[row][cpan]
// colsum (panel cpan rows, off-diag only)  -> partial[col][rpan]
__global__ __launch_bounds__(512, 4) void krowsum(const unsigned short* __restrict__ reps,
                                                  float* __restrict__ partial) {
    __shared__ unsigned short buf[2][64 * D];   // 2 x 32 KB B-chunk dbuf
    __shared__ float cs_lds[8][16][16];         // [wave][chunk*4+tile][col]
    const int lane = threadIdx.x & 63;
    const int w    = threadIdx.x >> 6;
    const int lrow = lane & 15;
    const int lkb  = (lane >> 4) * 16;
    const int swz  = (lrow & 7) << 4;

    // unrank blockIdx -> (rpan, cpan) with rpan <= cpan
    int bid = blockIdx.x, rpan = 0, rem = PAN;
    while (bid >= rem) { bid -= rem; ++rpan; --rem; }
    const int cpan = rpan + bid;
    const bool diag = (rpan == cpan);

    // ---- A fragments: direct global loads, once per block (64 VGPRs) ----
    bf16x8 afrag[RT][KC];
    #pragma unroll
    for (int rt = 0; rt < RT; ++rt) {
        const char* ar = (const char*)reps
                       + (size_t)(rpan * 256 + w * 32 + rt * 16 + lrow) * 512 + lkb;
        #pragma unroll
        for (int kc = 0; kc < KC; ++kc)
            afrag[rt][kc] = *(const bf16x8*)(ar + kc * 64);
    }

    float rs[RT][4];
    #pragma unroll
    for (int rt = 0; rt < RT; ++rt)
        #pragma unroll
        for (int e = 0; e < 4; ++e) rs[rt][e] = 0.f;

    // ---- B main loop: 4 chunks of 64 cols, double-buffered LDS ----
    const char* Bb = (const char*)reps + (size_t)cpan * 256 * 512;
    STAGE(&buf[0][0], Bb);
    __syncthreads();
    int cur = 0;
    for (int c = 0; c < 4; ++c) {
        if (c < 3) STAGE(&buf[cur ^ 1][0], Bb + (size_t)(c + 1) * 32768);
        const char* bb = (const char*)&buf[cur][0];
        float cs0 = 0.f, cs1 = 0.f, cs2 = 0.f, cs3 = 0.f;
        #pragma unroll
        for (int tp = 0; tp < 2; ++tp) {
            f32x4 acc[RT][2];
            #pragma unroll
            for (int rt = 0; rt < RT; ++rt) {
                acc[rt][0] = (f32x4){0.f, 0.f, 0.f, 0.f};
                acc[rt][1] = (f32x4){0.f, 0.f, 0.f, 0.f};
            }
            #pragma unroll
            for (int kc = 0; kc < KC; ++kc) {
                const int kb = (kc * 64 + lkb) ^ swz;
                bf16x8 bf0 = *(const bf16x8*)(bb + ((tp * 2 + 0) * 16 + lrow) * 512 + kb);
                bf16x8 bf1 = *(const bf16x8*)(bb + ((tp * 2 + 1) * 16 + lrow) * 512 + kb);
                #pragma unroll
                for (int rt = 0; rt < RT; ++rt) {
                    acc[rt][0] = __builtin_amdgcn_mfma_f32_16x16x32_bf16(
                        afrag[rt][kc], bf0, acc[rt][0], 0, 0, 0);
                    acc[rt][1] = __builtin_amdgcn_mfma_f32_16x16x32_bf16(
                        afrag[rt][kc], bf1, acc[rt][1], 0, 0, 0);
                }
            }
            // C/D layout: col = lane&15, row = (lane>>4)*4 + e  [m89]
            #pragma unroll
            for (int rt = 0; rt < RT; ++rt)
                #pragma unroll
                for (int e = 0; e < 4; ++e) {
                    float e0 = __builtin_amdgcn_exp2f(acc[rt][0][e] * CEXP);
                    float e1 = __builtin_amdgcn_exp2f(acc[rt][1][e] * CEXP);
                    rs[rt][e] += e0 + e1;
                    if (tp == 0) { cs0 += e0; cs1 += e1; }
                    else         { cs2 += e0; cs3 += e1; }
                }
        }
        if (!diag) {
            // colsum over this wave's 32 rows: reduce the 4 row-groups
            cs0 += __shfl_xor(cs0, 16); cs0 += __shfl_xor(cs0, 32);
            cs1 += __shfl_xor(cs1, 16); cs1 += __shfl_xor(cs1, 32);
            cs2 += __shfl_xor(cs2, 16); cs2 += __shfl_xor(cs2, 32);
            cs3 += __shfl_xor(cs3, 16); cs3 += __shfl_xor(cs3, 32);
            if (lane < 16) {
                cs_lds[w][c * 4 + 0][lane] = cs0;
                cs_lds[w][c * 4 + 1][lane] = cs1;
                cs_lds[w][c * 4 + 2][lane] = cs2;
                cs_lds[w][c * 4 + 3][lane] = cs3;
            }
        }
        __syncthreads();   // drains staging vmcnt + ds reads; publishes cs_lds
        cur ^= 1;
    }

    // ---- rowsum: reduce 16 col-lanes, write partial[row][cpan] ----
    #pragma unroll
    for (int rt = 0; rt < RT; ++rt)
        #pragma unroll
        for (int e = 0; e < 4; ++e)
            #pragma unroll
            for (int off = 1; off < 16; off <<= 1)
                rs[rt][e] += __shfl_xor(rs[rt][e], off);
    if ((lane & 15) == 0) {
        #pragma unroll
        for (int rt = 0; rt < RT; ++rt) {
            const int rg = rpan * 256 + w * 32 + rt * 16 + (lane >> 4) * 4;
            #pragma unroll
            for (int e = 0; e < 4; ++e)
                partial[(size_t)(rg + e) * SLOTS + cpan] = rs[rt][e];
        }
    }

    // ---- colsum: cross-wave sum (8 waves), write partial[col][rpan] ----
    if (!diag && threadIdx.x < 256) {
        const int ct  = threadIdx.x >> 4;    // chunk*4 + tile
        const int col = threadIdx.x & 15;
        float v = 0.f;
        #pragma unroll
        for (int ww = 0; ww < 8; ++ww) v += cs_lds[ww][ct][col];
        const int gcol = cpan * 256 + (ct >> 2) * 64 + (ct & 3) * 16 + col;
        partial[(size_t)gcol * SLOTS + rpan] = v;
    }
}

// ---- Kernel C1: per-row loss, block partial sums ----
__global__ __launch_bounds__(256) void kfinal1(const float* __restrict__ partial,
                                               const float* __restrict__ pos,
                                               float* __restrict__ bsum,
                                               int twoN, int n) {
    __shared__ float red[256];
    const int r = blockIdx.x * 256 + threadIdx.x;
    float s = 0.f;
    if (r < twoN) {
        const f32x4* pr = (const f32x4*)(partial + (size_t)r * SLOTS);
        f32x4 v = pr[0];
        #pragma unroll
        for (int q = 1; q < SLOTS / 4; ++q) {
            f32x4 u = pr[q];
            v[0] += u[0]; v[1] += u[1]; v[2] += u[2]; v[3] += u[3];
        }
        float dsum = (v[0] + v[1]) + (v[2] + v[3]) - E2;
        const float p = pos[r < n ? r : r - n];
        s = logf(dsum) - 2.0f * p;        // pos/T with T=0.5
    }
    red[threadIdx.x] = s;
    __syncthreads();
    #pragma unroll
    for (int off = 128; off; off >>= 1) {
        if (threadIdx.x < off) red[threadIdx.x] += red[threadIdx.x + off];
        __syncthreads();
    }
    if (threadIdx.x == 0) bsum[blockIdx.x] = red[0];
}

// ---- Kernel C2: final mean ----
__global__ __launch_bounds__(64) void kfinal2(const float* __restrict__ bsum,
                                              float* __restrict__ out, int twoN) {
    float s = threadIdx.x < FBLK ? bsum[threadIdx.x] : 0.f;
    #pragma unroll
    for (int off = 32; off; off >>= 1) s += __shfl_xor(s, off);
    if (threadIdx.x == 0) out[0] = s / (float)twoN;
}

extern "C" void kernel_launch(void* const* d_in, const int* in_sizes, int n_in,
                              void* d_out, int out_size, void* d_ws, size_t ws_size,
                              hipStream_t stream) {
    const float* zi = (const float*)d_in[0];
    const float* zj = (const float*)d_in[1];
    const int n    = in_sizes[0] / D;   // 4096
    const int twoN = 2 * n;             // 8192

    unsigned short* reps = (unsigned short*)d_ws;                   // 2N*D bf16 = 4 MB
    float* pos     = (float*)((char*)d_ws + (size_t)twoN * D * 2);  // N f32
    float* partial = pos + n;                                       // 2N*SLOTS f32
    float* bsum    = partial + (size_t)twoN * SLOTS;                // FBLK f32
    float* out     = (float*)d_out;

    knorm<<<n, 64, 0, stream>>>(zi, zj, reps, pos, n);
    krowsum<<<NBLK, 512, 0, stream>>>(reps, partial);
    kfinal1<<<FBLK, 256, 0, stream>>>(partial, pos, bsum, twoN, n);
    kfinal2<<<1, 64, 0, stream>>>(bsum, out, twoN);
}

// Round 7
// 55.998 us; speedup vs baseline: 1.5913x; 1.4234x over previous
//
#include <hip/hip_runtime.h>
#include <hip/hip_bf16.h>

// NT-Xent loss, fused + symmetric. N=4096, D=256, T=0.5.
// One 256x256 panel-pair tile serves rowsums of BOTH panels (row-reduce for
// panel r, col-reduce for panel c). 528 = 32*33/2 blocks, 8 waves x 32 rows.
// d_ws: [reps bf16 2N*D | pos f32 N | partial f32 2N*SLOTS | bsum f32 32]
// partial[row][slot]: slot p = contribution from panel p; single writer/slot.
// loss_i = log(sum_j exp(sim_ij/T) - e^2) - pos_i/T ; out = mean(loss)

#define D      256
#define KC     8            // K-chunks of 32 elems (D/32)
#define RT     2            // row-tiles per wave -> 32 rows/wave
#define PAN    32           // number of 256-row panels (8192/256)
#define NBLK   (PAN * (PAN + 1) / 2)   // 528 panel pairs
#define SLOTS  32           // partial slots per row (= PAN)
#define CEXP   2.885390081777926f  // 1/(T*ln2): exp(x/T) = 2^(x*CEXP)
#define E2     7.38905609893065f   // exp(1/T) = e^2, diagonal term
#define FBLK   32

typedef __bf16 bf16x8 __attribute__((ext_vector_type(8)));
typedef float  f32x4  __attribute__((ext_vector_type(4)));
typedef __attribute__((address_space(1))) const unsigned int* gas_t;
typedef __attribute__((address_space(3))) unsigned int*       las_t;

static __device__ __forceinline__ void gload_lds16(const void* g, void* l) {
    __builtin_amdgcn_global_load_lds((gas_t)(uintptr_t)g, (las_t)(uintptr_t)l, 16, 0, 0);
}

static __device__ __forceinline__ unsigned short f2bf(float x) {
    union { float f; unsigned u; } v; v.f = x;
    unsigned r = v.u + 0x7fffu + ((v.u >> 16) & 1u);   // RNE
    return (unsigned short)(r >> 16);
}

// Stage 32KB (64 rows x 512B) global->LDS with 512 threads (4 passes of 8KB).
// Linear LDS dest; source pre-swizzled so swizzled ds_reads see correct data.
#define STAGE(bufp, srcp)                                                 \
    do {                                                                  \
        const char* s_ = (const char*)(srcp);                             \
        char* d_ = (char*)(bufp);                                         \
        _Pragma("unroll")                                                 \
        for (int i_ = 0; i_ < 4; ++i_) {                                  \
            int o_   = i_ * 8192 + threadIdx.x * 16;                      \
            int row_ = o_ >> 9;                                           \
            int cb_  = o_ & 511;                                          \
            gload_lds16(s_ + row_ * 512 + (cb_ ^ ((row_ & 7) << 4)),      \
                        d_ + o_);                                         \
        }                                                                 \
    } while (0)

// ---- Kernel A: row L2-normalize both inputs -> bf16 reps; fp32 positives ----
__global__ __launch_bounds__(64) void knorm(const float* __restrict__ zi,
                                            const float* __restrict__ zj,
                                            unsigned short* __restrict__ reps,
                                            float* __restrict__ pos, int n) {
    const int i = blockIdx.x;
    const int lane = threadIdx.x;
    const float4 a = ((const float4*)(zi + (size_t)i * D))[lane];
    const float4 b = ((const float4*)(zj + (size_t)i * D))[lane];
    float si = a.x*a.x + a.y*a.y + a.z*a.z + a.w*a.w;
    float sj = b.x*b.x + b.y*b.y + b.z*b.z + b.w*b.w;
    float sd = a.x*b.x + a.y*b.y + a.z*b.z + a.w*b.w;
    #pragma unroll
    for (int off = 32; off; off >>= 1) {
        si += __shfl_xor(si, off);
        sj += __shfl_xor(sj, off);
        sd += __shfl_xor(sd, off);
    }
    const float inv_i = 1.0f / fmaxf(sqrtf(si), 1e-12f);
    const float inv_j = 1.0f / fmaxf(sqrtf(sj), 1e-12f);
    if (lane == 0) pos[i] = sd * inv_i * inv_j;
    ushort4 pa, pb;
    pa.x = f2bf(a.x * inv_i); pa.y = f2bf(a.y * inv_i);
    pa.z = f2bf(a.z * inv_i); pa.w = f2bf(a.w * inv_i);
    pb.x = f2bf(b.x * inv_j); pb.y = f2bf(b.y * inv_j);
    pb.z = f2bf(b.z * inv_j); pb.w = f2bf(b.w * inv_j);
    ((ushort4*)(reps + (size_t)i * D))[lane]       = pa;
    ((ushort4*)(reps + (size_t)(i + n) * D))[lane] = pb;
}

// ---- Kernel B: symmetric panel-pair exp-rowsum ----
// Block = unordered panel pair (rpan <= cpan). 8 waves x 32 rows.
// No min-waves launch bound: let the allocator use what it needs (R5/R6
// showed a 128-reg unified cap forces ~100MB/dispatch of scratch spill).
__global__ __launch_bounds__(512) void krowsum(const unsigned short* __restrict__ reps,
                                               float* __restrict__ partial) {
    __shared__ unsigned short buf[2][64 * D];   // 2 x 32 KB B-chunk dbuf
    __shared__ float cs_lds[8][16][16];         // [wave][chunk*4+tile][col]
    const int lane = threadIdx.x & 63;
    const int w    = threadIdx.x >> 6;
    const int lrow = lane & 15;
    const int lkb  = (lane >> 4) * 16;
    const int swz  = (lrow & 7) << 4;

    // unrank blockIdx -> (rpan, cpan) with rpan <= cpan
    int bid = blockIdx.x, rpan = 0, rem = PAN;
    while (bid >= rem) { bid -= rem; ++rpan; --rem; }
    const int cpan = rpan + bid;
    const bool diag = (rpan == cpan);

    // ---- issue first B-chunk stage, then A-fragment loads (overlap) ----
    const char* Bb = (const char*)reps + (size_t)cpan * 256 * 512;
    STAGE(&buf[0][0], Bb);

    bf16x8 afrag[RT][KC];
    #pragma unroll
    for (int rt = 0; rt < RT; ++rt) {
        const char* ar = (const char*)reps
                       + (size_t)(rpan * 256 + w * 32 + rt * 16 + lrow) * 512 + lkb;
        #pragma unroll
        for (int kc = 0; kc < KC; ++kc)
            afrag[rt][kc] = *(const bf16x8*)(ar + kc * 64);
    }

    float rs[RT][4];
    #pragma unroll
    for (int rt = 0; rt < RT; ++rt)
        #pragma unroll
        for (int e = 0; e < 4; ++e) rs[rt][e] = 0.f;

    __syncthreads();
    int cur = 0;
    for (int c = 0; c < 4; ++c) {
        if (c < 3) STAGE(&buf[cur ^ 1][0], Bb + (size_t)(c + 1) * 32768);
        const char* bb = (const char*)&buf[cur][0];
        float cs0 = 0.f, cs1 = 0.f, cs2 = 0.f, cs3 = 0.f;
        #pragma unroll
        for (int tp = 0; tp < 2; ++tp) {
            f32x4 acc[RT][2];
            #pragma unroll
            for (int rt = 0; rt < RT; ++rt) {
                acc[rt][0] = (f32x4){0.f, 0.f, 0.f, 0.f};
                acc[rt][1] = (f32x4){0.f, 0.f, 0.f, 0.f};
            }
            #pragma unroll
            for (int kc = 0; kc < KC; ++kc) {
                const int kb = (kc * 64 + lkb) ^ swz;
                bf16x8 bf0 = *(const bf16x8*)(bb + ((tp * 2 + 0) * 16 + lrow) * 512 + kb);
                bf16x8 bf1 = *(const bf16x8*)(bb + ((tp * 2 + 1) * 16 + lrow) * 512 + kb);
                #pragma unroll
                for (int rt = 0; rt < RT; ++rt) {
                    acc[rt][0] = __builtin_amdgcn_mfma_f32_16x16x32_bf16(
                        afrag[rt][kc], bf0, acc[rt][0], 0, 0, 0);
                    acc[rt][1] = __builtin_amdgcn_mfma_f32_16x16x32_bf16(
                        afrag[rt][kc], bf1, acc[rt][1], 0, 0, 0);
                }
            }
            // C/D layout: col = lane&15, row = (lane>>4)*4 + e  [m89]
            #pragma unroll
            for (int rt = 0; rt < RT; ++rt)
                #pragma unroll
                for (int e = 0; e < 4; ++e) {
                    float e0 = __builtin_amdgcn_exp2f(acc[rt][0][e] * CEXP);
                    float e1 = __builtin_amdgcn_exp2f(acc[rt][1][e] * CEXP);
                    rs[rt][e] += e0 + e1;
                    if (tp == 0) { cs0 += e0; cs1 += e1; }
                    else         { cs2 += e0; cs3 += e1; }
                }
        }
        if (!diag) {
            // colsum over this wave's 32 rows: reduce the 4 row-groups
            cs0 += __shfl_xor(cs0, 16); cs0 += __shfl_xor(cs0, 32);
            cs1 += __shfl_xor(cs1, 16); cs1 += __shfl_xor(cs1, 32);
            cs2 += __shfl_xor(cs2, 16); cs2 += __shfl_xor(cs2, 32);
            cs3 += __shfl_xor(cs3, 16); cs3 += __shfl_xor(cs3, 32);
            if (lane < 16) {
                cs_lds[w][c * 4 + 0][lane] = cs0;
                cs_lds[w][c * 4 + 1][lane] = cs1;
                cs_lds[w][c * 4 + 2][lane] = cs2;
                cs_lds[w][c * 4 + 3][lane] = cs3;
            }
        }
        __syncthreads();   // drains staging vmcnt + ds reads; publishes cs_lds
        cur ^= 1;
    }

    // ---- rowsum: reduce 16 col-lanes, write partial[row][cpan] ----
    #pragma unroll
    for (int rt = 0; rt < RT; ++rt)
        #pragma unroll
        for (int e = 0; e < 4; ++e)
            #pragma unroll
            for (int off = 1; off < 16; off <<= 1)
                rs[rt][e] += __shfl_xor(rs[rt][e], off);
    if ((lane & 15) == 0) {
        #pragma unroll
        for (int rt = 0; rt < RT; ++rt) {
            const int rg = rpan * 256 + w * 32 + rt * 16 + (lane >> 4) * 4;
            #pragma unroll
            for (int e = 0; e < 4; ++e)
                partial[(size_t)(rg + e) * SLOTS + cpan] = rs[rt][e];
        }
    }

    // ---- colsum: cross-wave sum (8 waves), write partial[col][rpan] ----
    if (!diag && threadIdx.x < 256) {
        const int ct  = threadIdx.x >> 4;    // chunk*4 + tile
        const int col = threadIdx.x & 15;
        float v = 0.f;
        #pragma unroll
        for (int ww = 0; ww < 8; ++ww) v += cs_lds[ww][ct][col];
        const int gcol = cpan * 256 + (ct >> 2) * 64 + (ct & 3) * 16 + col;
        partial[(size_t)gcol * SLOTS + rpan] = v;
    }
}

// ---- Kernel C1: per-row loss, block partial sums ----
__global__ __launch_bounds__(256) void kfinal1(const float* __restrict__ partial,
                                               const float* __restrict__ pos,
                                               float* __restrict__ bsum,
                                               int twoN, int n) {
    __shared__ float red[256];
    const int r = blockIdx.x * 256 + threadIdx.x;
    float s = 0.f;
    if (r < twoN) {
        const f32x4* pr = (const f32x4*)(partial + (size_t)r * SLOTS);
        f32x4 v = pr[0];
        #pragma unroll
        for (int q = 1; q < SLOTS / 4; ++q) {
            f32x4 u = pr[q];
            v[0] += u[0]; v[1] += u[1]; v[2] += u[2]; v[3] += u[3];
        }
        float dsum = (v[0] + v[1]) + (v[2] + v[3]) - E2;
        const float p = pos[r < n ? r : r - n];
        s = logf(dsum) - 2.0f * p;        // pos/T with T=0.5
    }
    red[threadIdx.x] = s;
    __syncthreads();
    #pragma unroll
    for (int off = 128; off; off >>= 1) {
        if (threadIdx.x < off) red[threadIdx.x] += red[threadIdx.x + off];
        __syncthreads();
    }
    if (threadIdx.x == 0) bsum[blockIdx.x] = red[0];
}

// ---- Kernel C2: final mean ----
__global__ __launch_bounds__(64) void kfinal2(const float* __restrict__ bsum,
                                              float* __restrict__ out, int twoN) {
    float s = threadIdx.x < FBLK ? bsum[threadIdx.x] : 0.f;
    #pragma unroll
    for (int off = 32; off; off >>= 1) s += __shfl_xor(s, off);
    if (threadIdx.x == 0) out[0] = s / (float)twoN;
}

extern "C" void kernel_launch(void* const* d_in, const int* in_sizes, int n_in,
                              void* d_out, int out_size, void* d_ws, size_t ws_size,
                              hipStream_t stream) {
    const float* zi = (const float*)d_in[0];
    const float* zj = (const float*)d_in[1];
    const int n    = in_sizes[0] / D;   // 4096
    const int twoN = 2 * n;             // 8192

    unsigned short* reps = (unsigned short*)d_ws;                   // 2N*D bf16 = 4 MB
    float* pos     = (float*)((char*)d_ws + (size_t)twoN * D * 2);  // N f32
    float* partial = pos + n;                                       // 2N*SLOTS f32
    float* bsum    = partial + (size_t)twoN * SLOTS;                // FBLK f32
    float* out     = (float*)d_out;

    knorm<<<n, 64, 0, stream>>>(zi, zj, reps, pos, n);
    krowsum<<<NBLK, 512, 0, stream>>>(reps, partial);
    kfinal1<<<FBLK, 256, 0, stream>>>(partial, pos, bsum, twoN, n);
    kfinal2<<<1, 64, 0, stream>>>(bsum, out, twoN);
}

// Round 8
// 54.370 us; speedup vs baseline: 1.6390x; 1.0299x over previous
//
#include <hip/hip_runtime.h>
#include <hip/hip_bf16.h>

// NT-Xent loss, fused + symmetric. N=4096, D=256, T=0.5.
// One 256x256 panel-pair tile serves rowsums of BOTH panels (row-reduce for
// panel r, col-reduce for panel c). 528 = 32*33/2 blocks, 8 waves x 32 rows.
// d_ws: [reps bf16 2N*D | pos f32 N | partial f32 SLOTS*2N | bsum f32 32]
// partial[slot][row] (TRANSPOSED: contiguous per-block writes, no 64B-line
// write amplification): slot p = contribution of panel p to row's denom.
// loss_i = log(sum_j exp(sim_ij/T) - e^2) - pos_i/T ; out = mean(loss)

#define D      256
#define KC     8            // K-chunks of 32 elems (D/32)
#define RT     2            // row-tiles per wave -> 32 rows/wave
#define PAN    32           // number of 256-row panels (8192/256)
#define NBLK   (PAN * (PAN + 1) / 2)   // 528 panel pairs
#define BN     32           // B-cols per LDS chunk (2x16KB dbuf + 8KB cs = 40KB)
#define SLOTS  32           // partial slots (= PAN)
#define CEXP   2.885390081777926f  // 1/(T*ln2): exp(x/T) = 2^(x*CEXP)
#define E2     7.38905609893065f   // exp(1/T) = e^2, diagonal term
#define FBLK   32

typedef __bf16 bf16x8 __attribute__((ext_vector_type(8)));
typedef float  f32x4  __attribute__((ext_vector_type(4)));
typedef __attribute__((address_space(1))) const unsigned int* gas_t;
typedef __attribute__((address_space(3))) unsigned int*       las_t;

static __device__ __forceinline__ void gload_lds16(const void* g, void* l) {
    __builtin_amdgcn_global_load_lds((gas_t)(uintptr_t)g, (las_t)(uintptr_t)l, 16, 0, 0);
}

static __device__ __forceinline__ unsigned short f2bf(float x) {
    union { float f; unsigned u; } v; v.f = x;
    unsigned r = v.u + 0x7fffu + ((v.u >> 16) & 1u);   // RNE
    return (unsigned short)(r >> 16);
}

// Stage 16KB (32 rows x 512B) global->LDS with 512 threads (2 passes of 8KB).
// Linear LDS dest; source pre-swizzled so swizzled ds_reads see correct data.
#define STAGE(bufp, srcp)                                                 \
    do {                                                                  \
        const char* s_ = (const char*)(srcp);                             \
        char* d_ = (char*)(bufp);                                         \
        _Pragma("unroll")                                                 \
        for (int i_ = 0; i_ < 2; ++i_) {                                  \
            int o_   = i_ * 8192 + threadIdx.x * 16;                      \
            int row_ = o_ >> 9;                                           \
            int cb_  = o_ & 511;                                          \
            gload_lds16(s_ + row_ * 512 + (cb_ ^ ((row_ & 7) << 4)),      \
                        d_ + o_);                                         \
        }                                                                 \
    } while (0)

// ---- Kernel A: row L2-normalize both inputs -> bf16 reps; fp32 positives ----
__global__ __launch_bounds__(64) void knorm(const float* __restrict__ zi,
                                            const float* __restrict__ zj,
                                            unsigned short* __restrict__ reps,
                                            float* __restrict__ pos, int n) {
    const int i = blockIdx.x;
    const int lane = threadIdx.x;
    const float4 a = ((const float4*)(zi + (size_t)i * D))[lane];
    const float4 b = ((const float4*)(zj + (size_t)i * D))[lane];
    float si = a.x*a.x + a.y*a.y + a.z*a.z + a.w*a.w;
    float sj = b.x*b.x + b.y*b.y + b.z*b.z + b.w*b.w;
    float sd = a.x*b.x + a.y*b.y + a.z*b.z + a.w*b.w;
    #pragma unroll
    for (int off = 32; off; off >>= 1) {
        si += __shfl_xor(si, off);
        sj += __shfl_xor(sj, off);
        sd += __shfl_xor(sd, off);
    }
    const float inv_i = 1.0f / fmaxf(sqrtf(si), 1e-12f);
    const float inv_j = 1.0f / fmaxf(sqrtf(sj), 1e-12f);
    if (lane == 0) pos[i] = sd * inv_i * inv_j;
    ushort4 pa, pb;
    pa.x = f2bf(a.x * inv_i); pa.y = f2bf(a.y * inv_i);
    pa.z = f2bf(a.z * inv_i); pa.w = f2bf(a.w * inv_i);
    pb.x = f2bf(b.x * inv_j); pb.y = f2bf(b.y * inv_j);
    pb.z = f2bf(b.z * inv_j); pb.w = f2bf(b.w * inv_j);
    ((ushort4*)(reps + (size_t)i * D))[lane]       = pa;
    ((ushort4*)(reps + (size_t)(i + n) * D))[lane] = pb;
}

// ---- Kernel B: symmetric panel-pair exp-rowsum ----
// Block = unordered panel pair (rpan <= cpan). 8 waves x 32 rows.
// LDS 40KB -> 2 blocks/CU (VGPR ~104 -> 4 waves/SIMD caps at exactly 2).
// 8 chunk-iterations, double-buffered staging.
__global__ __launch_bounds__(512) void krowsum(const unsigned short* __restrict__ reps,
                                               float* __restrict__ partial, int twoN) {
    __shared__ unsigned short buf[2][BN * D];   // 2 x 16 KB B-chunk dbuf
    __shared__ float cs_lds[8][16][16];         // [wave][tile][col], 8 KB
    const int lane = threadIdx.x & 63;
    const int w    = threadIdx.x >> 6;
    const int lrow = lane & 15;
    const int lkb  = (lane >> 4) * 16;
    const int swz  = (lrow & 7) << 4;

    // unrank blockIdx -> (rpan, cpan) with rpan <= cpan
    int bid = blockIdx.x, rpan = 0, rem = PAN;
    while (bid >= rem) { bid -= rem; ++rpan; --rem; }
    const int cpan = rpan + bid;
    const bool diag = (rpan == cpan);

    // ---- issue first B-chunk stage, then A-fragment loads (overlap) ----
    const char* Bb = (const char*)reps + (size_t)cpan * 256 * 512;
    STAGE(&buf[0][0], Bb);

    bf16x8 afrag[RT][KC];
    #pragma unroll
    for (int rt = 0; rt < RT; ++rt) {
        const char* ar = (const char*)reps
                       + (size_t)(rpan * 256 + w * 32 + rt * 16 + lrow) * 512 + lkb;
        #pragma unroll
        for (int kc = 0; kc < KC; ++kc)
            afrag[rt][kc] = *(const bf16x8*)(ar + kc * 64);
    }

    float rs[RT][4];
    #pragma unroll
    for (int rt = 0; rt < RT; ++rt)
        #pragma unroll
        for (int e = 0; e < 4; ++e) rs[rt][e] = 0.f;

    __syncthreads();
    int cur = 0;
    for (int c = 0; c < 8; ++c) {
        if (c < 7) STAGE(&buf[cur ^ 1][0], Bb + (size_t)(c + 1) * (BN * 512));
        const char* bb = (const char*)&buf[cur][0];
        f32x4 acc[RT][2];
        #pragma unroll
        for (int rt = 0; rt < RT; ++rt) {
            acc[rt][0] = (f32x4){0.f, 0.f, 0.f, 0.f};
            acc[rt][1] = (f32x4){0.f, 0.f, 0.f, 0.f};
        }
        #pragma unroll
        for (int kc = 0; kc < KC; ++kc) {
            const int kb = (kc * 64 + lkb) ^ swz;
            bf16x8 bf0 = *(const bf16x8*)(bb + (lrow)        * 512 + kb);
            bf16x8 bf1 = *(const bf16x8*)(bb + (16 + lrow)   * 512 + kb);
            #pragma unroll
            for (int rt = 0; rt < RT; ++rt) {
                acc[rt][0] = __builtin_amdgcn_mfma_f32_16x16x32_bf16(
                    afrag[rt][kc], bf0, acc[rt][0], 0, 0, 0);
                acc[rt][1] = __builtin_amdgcn_mfma_f32_16x16x32_bf16(
                    afrag[rt][kc], bf1, acc[rt][1], 0, 0, 0);
            }
        }
        // C/D layout: col = lane&15, row = (lane>>4)*4 + e  [m89]
        float cs0 = 0.f, cs1 = 0.f;
        #pragma unroll
        for (int rt = 0; rt < RT; ++rt)
            #pragma unroll
            for (int e = 0; e < 4; ++e) {
                float e0 = __builtin_amdgcn_exp2f(acc[rt][0][e] * CEXP);
                float e1 = __builtin_amdgcn_exp2f(acc[rt][1][e] * CEXP);
                rs[rt][e] += e0 + e1;
                cs0 += e0; cs1 += e1;
            }
        if (!diag) {
            // colsum over this wave's 32 rows: reduce the 4 row-groups
            cs0 += __shfl_xor(cs0, 16); cs0 += __shfl_xor(cs0, 32);
            cs1 += __shfl_xor(cs1, 16); cs1 += __shfl_xor(cs1, 32);
            if (lane < 16) {
                cs_lds[w][c * 2 + 0][lane] = cs0;
                cs_lds[w][c * 2 + 1][lane] = cs1;
            }
        }
        __syncthreads();   // drains staging vmcnt + ds reads; publishes cs_lds
        cur ^= 1;
    }

    // ---- rowsum: reduce 16 col-lanes, write partial[cpan][row] (f32x4) ----
    #pragma unroll
    for (int rt = 0; rt < RT; ++rt)
        #pragma unroll
        for (int e = 0; e < 4; ++e)
            #pragma unroll
            for (int off = 1; off < 16; off <<= 1)
                rs[rt][e] += __shfl_xor(rs[rt][e], off);
    if ((lane & 15) == 0) {
        #pragma unroll
        for (int rt = 0; rt < RT; ++rt) {
            const int rg = rpan * 256 + w * 32 + rt * 16 + (lane >> 4) * 4;
            f32x4 v = {rs[rt][0], rs[rt][1], rs[rt][2], rs[rt][3]};
            *(f32x4*)(partial + (size_t)cpan * twoN + rg) = v;
        }
    }

    // ---- colsum: cross-wave sum (8 waves), write partial[rpan][col] ----
    if (!diag && threadIdx.x < 256) {
        const int ct  = threadIdx.x >> 4;    // tile 0..15
        const int col = threadIdx.x & 15;
        float v = 0.f;
        #pragma unroll
        for (int ww = 0; ww < 8; ++ww) v += cs_lds[ww][ct][col];
        const int gcol = cpan * 256 + ct * 16 + col;
        partial[(size_t)rpan * twoN + gcol] = v;
    }
}

// ---- Kernel C1: per-row loss, block partial sums ----
__global__ __launch_bounds__(256) void kfinal1(const float* __restrict__ partial,
                                               const float* __restrict__ pos,
                                               float* __restrict__ bsum,
                                               int twoN, int n) {
    __shared__ float red[256];
    const int r = blockIdx.x * 256 + threadIdx.x;
    float s = 0.f;
    if (r < twoN) {
        float dsum = 0.f;
        #pragma unroll
        for (int p = 0; p < SLOTS; ++p) dsum += partial[(size_t)p * twoN + r];
        dsum -= E2;
        const float q = pos[r < n ? r : r - n];
        s = logf(dsum) - 2.0f * q;        // pos/T with T=0.5
    }
    red[threadIdx.x] = s;
    __syncthreads();
    #pragma unroll
    for (int off = 128; off; off >>= 1) {
        if (threadIdx.x < off) red[threadIdx.x] += red[threadIdx.x + off];
        __syncthreads();
    }
    if (threadIdx.x == 0) bsum[blockIdx.x] = red[0];
}

// ---- Kernel C2: final mean ----
__global__ __launch_bounds__(64) void kfinal2(const float* __restrict__ bsum,
                                              float* __restrict__ out, int twoN) {
    float s = threadIdx.x < FBLK ? bsum[threadIdx.x] : 0.f;
    #pragma unroll
    for (int off = 32; off; off >>= 1) s += __shfl_xor(s, off);
    if (threadIdx.x == 0) out[0] = s / (float)twoN;
}

extern "C" void kernel_launch(void* const* d_in, const int* in_sizes, int n_in,
                              void* d_out, int out_size, void* d_ws, size_t ws_size,
                              hipStream_t stream) {
    const float* zi = (const float*)d_in[0];
    const float* zj = (const float*)d_in[1];
    const int n    = in_sizes[0] / D;   // 4096
    const int twoN = 2 * n;             // 8192

    unsigned short* reps = (unsigned short*)d_ws;                   // 2N*D bf16 = 4 MB
    float* pos     = (float*)((char*)d_ws + (size_t)twoN * D * 2);  // N f32
    float* partial = pos + n;                                       // SLOTS*2N f32
    float* bsum    = partial + (size_t)SLOTS * twoN;                // FBLK f32
    float* out     = (float*)d_out;

    knorm<<<n, 64, 0, stream>>>(zi, zj, reps, pos, n);
    krowsum<<<NBLK, 512, 0, stream>>>(reps, partial, twoN);
    kfinal1<<<FBLK, 256, 0, stream>>>(partial, pos, bsum, twoN, n);
    kfinal2<<<1, 64, 0, stream>>>(bsum, out, twoN);
}